// Round 8
// baseline (74.044 us; speedup 1.0000x reference)
//
#include <hip/hip_runtime.h>
#include <hip/hip_bf16.h>
#include <cstdint>

// PiNet: B=8192, I=12, O=512, DEG=4.
// Symmetry-folded to T = 1820 monomials (padded to 1856 = 29*64).
// R7: monomial matrix M materialized by pinet_mfeat (fp16, pack-of-8 layout);
// GEMM is now a pure MFMA pipeline: A via global_load_lds DMA, B from L2.

#define NB 8192
#define NI 12
#define NO 512
#define T_TOTAL 1820
#define TPAD 1856          // 29 * 64
#define NKT 29
#define NOCT 232           // TPAD / 8
#define B2 13
#define B3 91
#define B4 455

typedef __attribute__((ext_vector_type(8))) _Float16 f16x8;
typedef __attribute__((ext_vector_type(4))) float f32x4;

#define MFMA16(a, b, c) __builtin_amdgcn_mfma_f32_16x16x32_f16(a, b, c, 0, 0, 0)

__device__ __forceinline__ void async_copy16(const void* g, void* l) {
    __builtin_amdgcn_global_load_lds(
        (const __attribute__((address_space(1))) uint32_t*)g,
        (__attribute__((address_space(3))) uint32_t*)l, 16, 0, 0);
}

__device__ __forceinline__ int H2f(int n) { return n * (n + 1) / 2; }
__device__ __forceinline__ int H3f(int n) { return n * (n + 1) * (n + 2) / 6; }
__device__ __forceinline__ int rank2(int a, int b) {
    int r = 0;
    for (int j = 0; j < a; ++j) r += NI - j;
    return r + (b - a);
}

// ---------- maps: mp (monomial pair table) + tup/rk orbit descriptors ----------
__global__ __launch_bounds__(256) void pinet_maps(
    uint32_t* __restrict__ mp,
    ushort* __restrict__ tup2, float* __restrict__ rk2,
    ushort* __restrict__ tup3, float* __restrict__ rk3,
    ushort* __restrict__ tup4, float* __restrict__ rk4) {
    int id = blockIdx.x * 256 + threadIdx.x;
    if (id < TPAD) {
        int t = id;
        uint32_t v = 0;
        if (t == 0) {
            v = 0;
        } else if (t < B2) {
            v = (uint32_t)t;
        } else if (t < B3) {
            int r = t - B2;
            int a = 0; while (r >= (NI - a)) { r -= (NI - a); ++a; }
            int b = a + r;
            v = (uint32_t)(1 + a) | ((uint32_t)(1 + b) << 16);
        } else if (t < B4) {
            int r = t - B3;
            int a = 0; while (r >= H2f(NI - a)) { r -= H2f(NI - a); ++a; }
            int b = a; while (r >= (NI - b)) { r -= (NI - b); ++b; }
            int c = b + r;
            v = (uint32_t)(13 + rank2(a, b)) | ((uint32_t)(1 + c) << 16);
        } else if (t < T_TOTAL) {
            int r = t - B4;
            int a = 0; while (r >= H3f(NI - a)) { r -= H3f(NI - a); ++a; }
            int b = a; while (r >= H2f(NI - b)) { r -= H2f(NI - b); ++b; }
            int c = b; while (r >= (NI - c)) { r -= (NI - c); ++c; }
            int d = c + r;
            v = (uint32_t)(13 + rank2(a, b)) | ((uint32_t)(13 + rank2(c, d)) << 16);
        }
        mp[t] = v;     // t in [1820,1856): monomial = 1, weight 0
        return;
    }
    id -= TPAD;
    if (id < 1365) {                      // degree 4
        int r = id;
        int a = 0; while (r >= H3f(NI - a)) { r -= H3f(NI - a); ++a; }
        int b = a; while (r >= H2f(NI - b)) { r -= H2f(NI - b); ++b; }
        int c = b; while (r >= (NI - c)) { r -= (NI - c); ++c; }
        int d = c + r;
        tup4[id] = (ushort)(a | (b << 4) | (c << 8) | (d << 12));
        int k = 1, run = 1;
        if (b == a) { ++run; k *= run; } else run = 1;
        if (c == b) { ++run; k *= run; } else run = 1;
        if (d == c) { ++run; k *= run; } else run = 1;
        rk4[id] = 1.0f / (float)k;
        return;
    }
    id -= 1365;
    if (id < 364) {                       // degree 3
        int r = id;
        int a = 0; while (r >= H2f(NI - a)) { r -= H2f(NI - a); ++a; }
        int b = a; while (r >= (NI - b)) { r -= (NI - b); ++b; }
        int c = b + r;
        tup3[id] = (ushort)(a | (b << 4) | (c << 8));
        int k = 1, run = 1;
        if (b == a) { ++run; k *= run; } else run = 1;
        if (c == b) { ++run; k *= run; } else run = 1;
        rk3[id] = 1.0f / (float)k;
        return;
    }
    id -= 364;
    if (id < 78) {                        // degree 2
        int r = id;
        int a = 0; while (r >= (NI - a)) { r -= (NI - a); ++a; }
        int b = a + r;
        tup2[id] = (ushort)(a | (b << 4));
        rk2[id] = (a == b) ? 0.5f : 1.0f;
    }
}

// ---------- mfeat: materialize M[oct][b][8] fp16 (pack-of-8 t per b) ----------
// One block = 32 b x 32 tasks; grid 256.
__global__ __launch_bounds__(1024) void pinet_mfeat(
    const float* __restrict__ x, const uint32_t* __restrict__ mp,
    ushort* __restrict__ M) {
    __shared__ float msm[32][93];
    const int tid = threadIdx.x;
    const int b0 = blockIdx.x * 32;

    for (int idx = tid; idx < 32 * 13; idx += 1024) {
        int b = idx / 13, j = idx % 13;
        msm[b][j] = (j == 0) ? 1.0f : x[(b0 + b) * 12 + (j - 1)];
    }
    __syncthreads();
    for (int idx = tid; idx < 32 * 78; idx += 1024) {
        int b = idx / 78, q = idx % 78;
        uint32_t m2 = mp[B2 + q];
        msm[b][13 + q] = msm[b][m2 & 0xFFFFu] * msm[b][m2 >> 16];
    }
    __syncthreads();

    const int bl = tid & 31, task = tid >> 5;
    const float* row = msm[bl];
    for (int oct = task; oct < NOCT; oct += 32) {
        uint4 ma = *(const uint4*)&mp[oct * 8];
        uint4 mb = *(const uint4*)&mp[oct * 8 + 4];
        uint32_t mqs[8] = {ma.x, ma.y, ma.z, ma.w, mb.x, mb.y, mb.z, mb.w};
        uint32_t pk[4];
#pragma unroll
        for (int j = 0; j < 4; ++j) {
            float p0 = row[mqs[2 * j] & 0xFFFFu] * row[mqs[2 * j] >> 16];
            float p1 = row[mqs[2 * j + 1] & 0xFFFFu] * row[mqs[2 * j + 1] >> 16];
            _Float16 h0 = (_Float16)p0, h1 = (_Float16)p1;
            pk[j] = (uint32_t)__builtin_bit_cast(unsigned short, h0) |
                    ((uint32_t)__builtin_bit_cast(unsigned short, h1) << 16);
        }
        *(uint4*)&M[((size_t)oct * NB + b0 + bl) * 8] =
            make_uint4(pk[0], pk[1], pk[2], pk[3]);
    }
}

// ---------- fold: stage row in LDS, per-t orbit gather, plain stores ----------
// One block (1024 threads) per o. Output Wh fp16, pack-of-8 layout:
// Wh[((t>>3)*512 + o)*8 + (t&7)].
__global__ __launch_bounds__(1024) void pinet_fold(
    const float* __restrict__ w0, const float* __restrict__ w1,
    const float* __restrict__ w2, const float* __restrict__ w3,
    const float* __restrict__ w4,
    const ushort* __restrict__ tup2, const float* __restrict__ rk2,
    const ushort* __restrict__ tup3, const float* __restrict__ rk3,
    const ushort* __restrict__ tup4, const float* __restrict__ rk4,
    ushort* __restrict__ Wh) {
    __shared__ float sw4[20736];
    __shared__ float sw3[1728];
    __shared__ float sw2[144];
    const int tid = threadIdx.x;
    const int o = blockIdx.x;

    {   // coalesced staging
        const float4* g4 = (const float4*)(w4 + o * 20736);
        float4* s4 = (float4*)sw4;
        for (int i = tid; i < 5184; i += 1024) s4[i] = g4[i];
        if (tid < 432) ((float4*)sw3)[tid] = ((const float4*)(w3 + o * 1728))[tid];
        if (tid < 36)  ((float4*)sw2)[tid] = ((const float4*)(w2 + o * 144))[tid];
    }
    __syncthreads();

#define W4P(p, q, r, s_) sw4[(p) * 1728 + (q) * 144 + (r) * 12 + (s_)]
#define W3P(p, q, r)     sw3[(p) * 144 + (q) * 12 + (r)]
    for (int t = tid; t < TPAD; t += 1024) {
        float s = 0.0f;
        if (t == 0) {
            s = w0[o];
        } else if (t < B2) {
            s = w1[o * 12 + (t - 1)];
        } else if (t < B3) {
            int q = t - B2; int tp = tup2[q];
            int a = tp & 15, b = (tp >> 4) & 15;
            s = (sw2[a * 12 + b] + sw2[b * 12 + a]) * rk2[q];
        } else if (t < B4) {
            int q = t - B3; int tp = tup3[q];
            int a = tp & 15, b = (tp >> 4) & 15, c = (tp >> 8) & 15;
            s = (W3P(a, b, c) + W3P(a, c, b) + W3P(b, a, c) +
                 W3P(b, c, a) + W3P(c, a, b) + W3P(c, b, a)) * rk3[q];
        } else if (t < T_TOTAL) {
            int q = t - B4; int tp = tup4[q];
            int a = tp & 15, b = (tp >> 4) & 15, c = (tp >> 8) & 15, d = (tp >> 12) & 15;
            float s4v =
                W4P(a,b,c,d) + W4P(a,b,d,c) + W4P(a,c,b,d) + W4P(a,c,d,b) +
                W4P(a,d,b,c) + W4P(a,d,c,b) + W4P(b,a,c,d) + W4P(b,a,d,c) +
                W4P(b,c,a,d) + W4P(b,c,d,a) + W4P(b,d,a,c) + W4P(b,d,c,a) +
                W4P(c,a,b,d) + W4P(c,a,d,b) + W4P(c,b,a,d) + W4P(c,b,d,a) +
                W4P(c,d,a,b) + W4P(c,d,b,a) + W4P(d,a,b,c) + W4P(d,a,c,b) +
                W4P(d,b,a,c) + W4P(d,b,c,a) + W4P(d,c,a,b) + W4P(d,c,b,a);
            s = s4v * rk4[q];
        }
        _Float16 h = (_Float16)s;
        Wh[((t >> 3) * NO + o) * 8 + (t & 7)] = __builtin_bit_cast(unsigned short, h);
    }
#undef W4P
#undef W3P
}

// ---------- MFMA GEMM: out[b,o] = sum_t M[t][b] * Wt[t][o], fp16 ----------
// Block: 64 b x 256 o, 1024 threads (16 waves = 2wB x 8wO), wave 32b x 32o.
// A staged via global_load_lds DMA (double-buffered), B direct from L2.
__global__ __launch_bounds__(1024, 4) void pinet_gemm(
    const ushort* __restrict__ M, const ushort* __restrict__ Wh,
    float* __restrict__ out) {
    __shared__ ushort Ash[2][8][64][8];   // [buf][oct][b][8 fp16] = 16 KB

    const int tid = threadIdx.x;
    const int blkB = blockIdx.x >> 1;
    const int blkO = blockIdx.x & 1;
    const int b0 = blkB * 64;

    const int l = tid & 63, w = tid >> 6;
    const int lm = l & 15, lg = l >> 4;
    const int wB = w >> 3, wO = w & 7;
    const int o_w = blkO * 256 + wO * 32;
    const int soct = tid >> 6, sb = tid & 63;   // staging role (waves 0..7)

    f32x4 acc[2][2] = {};

    auto stage = [&](int kt, int buf) {
        if (tid < 512) {
            const uint32_t* g = (const uint32_t*)
                (M + (((size_t)(kt * 8 + soct)) * NB + b0 + sb) * 8);
            async_copy16(g, (void*)&Ash[buf][soct][0][0]);   // lane sb -> +16B*sb
        }
    };

    stage(0, 0);
    asm volatile("s_waitcnt vmcnt(0)" ::: "memory");
    __syncthreads();

    for (int kt = 0; kt < NKT; ++kt) {
        const int buf = kt & 1;
        if (kt + 1 < NKT) stage(kt + 1, buf ^ 1);

        f16x8 Bv[2][2];
#pragma unroll
        for (int os = 0; os < 2; ++os)
#pragma unroll
            for (int c = 0; c < 2; ++c) {
                int pk = kt * 8 + c * 4 + lg;
                Bv[os][c] = *(const f16x8*)
                    (Wh + ((size_t)pk * NO + o_w + os * 16 + lm) * 8);
            }
#pragma unroll
        for (int c = 0; c < 2; ++c) {
            f16x8 a0 = *(const f16x8*)&Ash[buf][c * 4 + lg][wB * 32 + lm][0];
            f16x8 a1 = *(const f16x8*)&Ash[buf][c * 4 + lg][wB * 32 + 16 + lm][0];
            acc[0][0] = MFMA16(a0, Bv[0][c], acc[0][0]);
            acc[0][1] = MFMA16(a0, Bv[1][c], acc[0][1]);
            acc[1][0] = MFMA16(a1, Bv[0][c], acc[1][0]);
            acc[1][1] = MFMA16(a1, Bv[1][c], acc[1][1]);
        }
        asm volatile("s_waitcnt vmcnt(0)" ::: "memory");
        __syncthreads();
    }

#pragma unroll
    for (int bs = 0; bs < 2; ++bs)
#pragma unroll
        for (int os = 0; os < 2; ++os) {
            int ob = o_w + os * 16 + lm;
#pragma unroll
            for (int r = 0; r < 4; ++r) {
                int bb = b0 + wB * 32 + bs * 16 + lg * 4 + r;
                out[bb * NO + ob] = acc[bs][os][r];
            }
        }
}

extern "C" void kernel_launch(void* const* d_in, const int* in_sizes, int n_in,
                              void* d_out, int out_size, void* d_ws, size_t ws_size,
                              hipStream_t stream) {
    const float* x  = (const float*)d_in[0];
    const float* w0 = (const float*)d_in[1];
    const float* w1 = (const float*)d_in[2];
    const float* w2 = (const float*)d_in[3];
    const float* w3 = (const float*)d_in[4];
    const float* w4 = (const float*)d_in[5];
    float* out = (float*)d_out;

    uint8_t* ws = (uint8_t*)d_ws;
    uint32_t* mp  = (uint32_t*)ws;                 // 7424 B (pad 8192)
    ushort* tup4  = (ushort*)(ws + 8192);          // 2730 B (pad 3072)
    float*  rk4   = (float*)(ws + 11264);          // 5460 B (pad 5632)
    ushort* tup3  = (ushort*)(ws + 16896);         // 728 B  (pad 1024)
    float*  rk3   = (float*)(ws + 17920);          // 1456 B (pad 1536)
    ushort* tup2  = (ushort*)(ws + 19456);         // 156 B  (pad 512)
    float*  rk2   = (float*)(ws + 19968);          // 312 B  (pad 512)
    ushort* Wh    = (ushort*)(ws + 20480);         // 232*512*8*2 = 1,900,544 B
    ushort* M     = (ushort*)(ws + 20480 + 1900544); // 232*8192*8*2 = 30,408,704 B

    pinet_maps<<<15, 256, 0, stream>>>(mp, tup2, rk2, tup3, rk3, tup4, rk4);
    pinet_mfeat<<<NB / 32, 1024, 0, stream>>>(x, mp, M);
    pinet_fold<<<NO, 1024, 0, stream>>>(w0, w1, w2, w3, w4,
                                        tup2, rk2, tup3, rk3, tup4, rk4, Wh);
    pinet_gemm<<<(NB / 64) * 2, 1024, 0, stream>>>(M, Wh, out);
}